// Round 1
// baseline (405.677 us; speedup 1.0000x reference)
//
#include <hip/hip_runtime.h>

// BlockMaskGenerator: B=8192, NUM_BLOCKS=4, H=W=64, S=4096.
// Outputs (int32, concatenated): context[B*S], target[B*S], positions[B*S], counts[B].
//
// v2 structure:
//  - bm_params: 32768 threads compute each target-block rectangle ONCE
//    (sqrt/div/trunc), packed (top|bot<<8|lft<<16|rgt<<24) into d_ws.
//  - bm_main: one 256-thread block per batch row.
//      * one wave-uniform dwordx4 load of the 4 packed rects (vs 12 loads + 4
//        sqrt + 4 div per thread before)
//      * membership via per-rect 64-bit column masks; mask16 = (rowmask>>c0)
//      * branchless stable-partition LDS scatter (prefix-popc address, ONE
//        ds_write per element vs two divergent before)
//      * coalesced int4 mask stores + LDS-staged coalesced positions stores
//        (unchanged — already stream-friendly)

#define NBLK 4
#define HGT 64
#define WID 64
#define SEQ 4096

__device__ __forceinline__ unsigned pack_rect(float sc, float rt, float rl) {
    float s = __fadd_rn(0.15f, __fmul_rn(sc, 0.05f));            // no FMA contraction
    int area = (int)__fmul_rn(__fmul_rn(s, 64.0f), 64.0f);       // trunc
    int bh = (int)__fsqrt_rn((float)area);                       // IEEE sqrt, trunc
    bh = min(max(bh, 1), HGT);
    int bw = (int)__fdiv_rn((float)area, (float)bh);             // IEEE div, trunc
    bw = min(max(bw, 1), WID);
    int maxt = max(HGT - bh + 1, 1);
    int maxl = max(WID - bw + 1, 1);
    int tp = (int)__fmul_rn(rt, (float)maxt);
    int lf = (int)__fmul_rn(rl, (float)maxl);
    return (unsigned)tp | ((unsigned)(tp + bh) << 8)
         | ((unsigned)lf << 16) | ((unsigned)(lf + bw) << 24);
}

__global__ __launch_bounds__(256) void bm_params(
    const float* __restrict__ scales,
    const float* __restrict__ rand_tops,
    const float* __restrict__ rand_lefts,
    unsigned int* __restrict__ rects, int TB)
{
    int t = blockIdx.x * 256 + threadIdx.x;
    if (t < TB) rects[t] = pack_rect(scales[t], rand_tops[t], rand_lefts[t]);
}

template <bool USE_WS>
__global__ __launch_bounds__(256) void bm_main(
    const float* __restrict__ scales,
    const float* __restrict__ rand_tops,
    const float* __restrict__ rand_lefts,
    const uint4* __restrict__ rects4,
    int* __restrict__ out, int B)
{
    __shared__ int pos_s[SEQ];   // 16 KB
    __shared__ int wsum[4];

    const int b   = blockIdx.x;
    const int tid = threadIdx.x;

    // --- fetch packed rects (wave-uniform -> scalarizable) ---
    unsigned rv[NBLK];
    if (USE_WS) {
        uint4 rp = rects4[b];
        rv[0] = rp.x; rv[1] = rp.y; rv[2] = rp.z; rv[3] = rp.w;
    } else {
#pragma unroll
        for (int j = 0; j < NBLK; ++j) {
            int t = b * NBLK + j;
            rv[j] = pack_rect(scales[t], rand_tops[t], rand_lefts[t]);
        }
    }

    int top[NBLK], bot[NBLK];
    unsigned long long cmask[NBLK];
#pragma unroll
    for (int j = 0; j < NBLK; ++j) {
        unsigned v = rv[j];
        top[j] = (int)(v & 0xffu);
        bot[j] = (int)((v >> 8) & 0xffu);
        int lf = (int)((v >> 16) & 0xffu);
        int bw = (int)((v >> 24) & 0xffu) - lf;
        unsigned long long m = (bw >= 64) ? ~0ull : ((1ull << bw) - 1ull);
        cmask[j] = m << lf;
    }

    // --- scan ownership: 16 consecutive positions (row r, cols [c0,c0+16)) ---
    const int p0 = tid * 16;
    const int r  = p0 >> 6;
    const int c0 = p0 & 63;
    unsigned long long rm = 0ull;
#pragma unroll
    for (int j = 0; j < NBLK; ++j)
        if (r >= top[j] && r < bot[j]) rm |= cmask[j];
    const unsigned mask16 = (unsigned)(rm >> c0) & 0xffffu;
    const int cnt = __popc(mask16);

    // --- block-wide inclusive scan over 256 threads (wave=64) ---
    const int lane = tid & 63;
    const int wv   = tid >> 6;
    int v = cnt;
#pragma unroll
    for (int d = 1; d < 64; d <<= 1) {
        int t = __shfl_up(v, d, 64);
        if (lane >= d) v += t;
    }
    if (lane == 63) wsum[wv] = v;
    __syncthreads();
    int waveOff = 0, total = 0;
#pragma unroll
    for (int w = 0; w < 4; ++w) {
        int ws = wsum[w];
        if (w < wv) waveOff += ws;
        total += ws;
    }
    const int base_t = waveOff + (v - cnt);   // # targets before p0

    // --- branchless stable-partition scatter into LDS ---
#pragma unroll
    for (int k = 0; k < 16; ++k) {
        int tpre = __popc(mask16 & ((1u << k) - 1u));        // targets in strip below k
        int a_t  = base_t + tpre;                            // target rank
        int a_n  = total + (p0 - base_t) + (k - tpre);       // total + nontarget rank
        int addr = ((mask16 >> k) & 1u) ? a_t : a_n;         // cndmask, no divergence
        pos_s[addr] = p0 + k;
    }

    // --- coalesced mask stores (independent ownership: int4 at g*256+tid) ---
    const size_t BS = (size_t)B * SEQ;
    int4* ctx4 = (int4*)out        + (size_t)b * (SEQ / 4);
    int4* tgt4 = (int4*)(out + BS) + (size_t)b * (SEQ / 4);
#pragma unroll
    for (int g = 0; g < 4; ++g) {
        int vidx = g * 256 + tid;
        int p  = vidx * 4;
        int rr = p >> 6;
        int cc = p & 63;
        unsigned long long rmg = 0ull;
#pragma unroll
        for (int j = 0; j < NBLK; ++j)
            if (rr >= top[j] && rr < bot[j]) rmg |= cmask[j];
        int m4 = (int)((rmg >> cc) & 0xfull);
        int4 tv, cv;
        tv.x =  m4       & 1; tv.y = (m4 >> 1) & 1;
        tv.z = (m4 >> 2) & 1; tv.w = (m4 >> 3) & 1;
        cv.x = tv.x ^ 1; cv.y = tv.y ^ 1; cv.z = tv.z ^ 1; cv.w = tv.w ^ 1;
        tgt4[vidx] = tv;
        ctx4[vidx] = cv;
    }

    // --- stream positions out of LDS, fully coalesced ---
    __syncthreads();
    const int4* ps4 = (const int4*)pos_s;
    int4* pout4 = (int4*)(out + 2 * BS) + (size_t)b * (SEQ / 4);
#pragma unroll
    for (int g = 0; g < 4; ++g) {
        int vidx = g * 256 + tid;
        pout4[vidx] = ps4[vidx];
    }

    if (tid == 0) out[3 * BS + (size_t)b] = total;
}

extern "C" void kernel_launch(void* const* d_in, const int* in_sizes, int n_in,
                              void* d_out, int out_size, void* d_ws, size_t ws_size,
                              hipStream_t stream) {
    const float* scales     = (const float*)d_in[0];
    const float* rand_tops  = (const float*)d_in[1];
    const float* rand_lefts = (const float*)d_in[2];
    int* out = (int*)d_out;
    const int TB = in_sizes[0];          // 32768
    const int B  = TB / NBLK;            // 8192

    if (ws_size >= (size_t)TB * sizeof(unsigned int)) {
        unsigned int* rects = (unsigned int*)d_ws;
        bm_params<<<(TB + 255) / 256, 256, 0, stream>>>(scales, rand_tops, rand_lefts, rects, TB);
        bm_main<true><<<B, 256, 0, stream>>>(scales, rand_tops, rand_lefts,
                                             (const uint4*)rects, out, B);
    } else {
        bm_main<false><<<B, 256, 0, stream>>>(scales, rand_tops, rand_lefts,
                                              nullptr, out, B);
    }
}

// Round 2
// 401.648 us; speedup vs baseline: 1.0100x; 1.0100x over previous
//
#include <hip/hip_runtime.h>

// BlockMaskGenerator: B=8192, NUM_BLOCKS=4, H=W=64, S=4096.
// Outputs (int32, concatenated): context[B*S], target[B*S], positions[B*S], counts[B].
//
// v3: single kernel again (bm_params launch was measured-neutral -3us).
// KEY CHANGE vs v1/v2: the stable-partition scatter into LDS had inter-lane
// stride of 16 dwords -> all even lanes on one bank, all odd lanes on another
// (32-way conflict, ~11x per ds_write, ~55us of LDS-pipe serialization).
// Fix: skewed addressing phys(a) = a + (a>>5). Scatter spreads to 2 lanes/bank
// (free); read-back stays 4-consecutive-dword per thread (2 lanes/bank, free)
// and global position stores remain int4-coalesced.

#define NBLK 4
#define HGT 64
#define WID 64
#define SEQ 4096
#define SKEW(a) ((a) + ((a) >> 5))

__global__ __launch_bounds__(256) void blockmask_kernel(
    const float* __restrict__ scales,
    const float* __restrict__ rand_tops,
    const float* __restrict__ rand_lefts,
    int* __restrict__ out,
    int B)
{
    __shared__ int pos_s[SEQ + (SEQ >> 5)];   // 16.5 KB, skewed layout
    __shared__ int wsum[4];

    const int b   = blockIdx.x;
    const int tid = threadIdx.x;

    // --- per-batch rectangles (computed redundantly; VALU proven non-binding) ---
    int top[NBLK], bot[NBLK];
    unsigned long long cmask[NBLK];
#pragma unroll
    for (int j = 0; j < NBLK; ++j) {
        int t = b * NBLK + j;
        float sc = scales[t];
        float s = __fadd_rn(0.15f, __fmul_rn(sc, 0.05f));           // no FMA contraction
        int area = (int)__fmul_rn(__fmul_rn(s, 64.0f), 64.0f);      // trunc
        int bh = (int)__fsqrt_rn((float)area);                      // IEEE sqrt, trunc
        bh = min(max(bh, 1), HGT);
        int bw = (int)__fdiv_rn((float)area, (float)bh);            // IEEE div, trunc
        bw = min(max(bw, 1), WID);
        int maxt = max(HGT - bh + 1, 1);
        int maxl = max(WID - bw + 1, 1);
        int tp = (int)__fmul_rn(rand_tops[t],  (float)maxt);
        int lf = (int)__fmul_rn(rand_lefts[t], (float)maxl);
        top[j] = tp; bot[j] = tp + bh;
        unsigned long long m = (bw >= 64) ? ~0ull : ((1ull << bw) - 1ull);
        cmask[j] = m << lf;
    }

    // --- scan ownership: 16 consecutive positions (row r, cols [c0,c0+16)) ---
    const int p0 = tid * 16;
    const int r  = p0 >> 6;
    const int c0 = p0 & 63;
    unsigned long long rm = 0ull;
#pragma unroll
    for (int j = 0; j < NBLK; ++j)
        if (r >= top[j] && r < bot[j]) rm |= cmask[j];
    const unsigned mask16 = (unsigned)(rm >> c0) & 0xffffu;
    const int cnt = __popc(mask16);

    // --- block-wide inclusive scan over 256 threads (wave=64) ---
    const int lane = tid & 63;
    const int wv   = tid >> 6;
    int v = cnt;
#pragma unroll
    for (int d = 1; d < 64; d <<= 1) {
        int t = __shfl_up(v, d, 64);
        if (lane >= d) v += t;
    }
    if (lane == 63) wsum[wv] = v;
    __syncthreads();
    int waveOff = 0, total = 0;
#pragma unroll
    for (int w = 0; w < 4; ++w) {
        int ws = wsum[w];
        if (w < wv) waveOff += ws;
        total += ws;
    }
    const int base_t = waveOff + (v - cnt);   // # targets before p0

    // --- branchless stable-partition scatter into SKEWED LDS (conflict-free) ---
#pragma unroll
    for (int k = 0; k < 16; ++k) {
        int tpre = __popc(mask16 & ((1u << k) - 1u));        // targets in strip below k
        int a_t  = base_t + tpre;                            // target rank
        int a_n  = total + (p0 - base_t) + (k - tpre);       // total + nontarget rank
        int addr = ((mask16 >> k) & 1u) ? a_t : a_n;         // cndmask, no divergence
        pos_s[SKEW(addr)] = p0 + k;
    }

    // --- coalesced mask stores (independent ownership: int4 at g*256+tid) ---
    const size_t BS = (size_t)B * SEQ;
    int4* ctx4 = (int4*)out        + (size_t)b * (SEQ / 4);
    int4* tgt4 = (int4*)(out + BS) + (size_t)b * (SEQ / 4);
#pragma unroll
    for (int g = 0; g < 4; ++g) {
        int vidx = g * 256 + tid;
        int p  = vidx * 4;
        int rr = p >> 6;
        int cc = p & 63;
        unsigned long long rmg = 0ull;
#pragma unroll
        for (int j = 0; j < NBLK; ++j)
            if (rr >= top[j] && rr < bot[j]) rmg |= cmask[j];
        int m4 = (int)((rmg >> cc) & 0xfull);
        int4 tv, cv;
        tv.x =  m4       & 1; tv.y = (m4 >> 1) & 1;
        tv.z = (m4 >> 2) & 1; tv.w = (m4 >> 3) & 1;
        cv.x = tv.x ^ 1; cv.y = tv.y ^ 1; cv.z = tv.z ^ 1; cv.w = tv.w ^ 1;
        tgt4[vidx] = tv;
        ctx4[vidx] = cv;
    }

    // --- stream positions out of skewed LDS, coalesced int4 global stores ---
    __syncthreads();
    int4* pout4 = (int4*)(out + 2 * BS) + (size_t)b * (SEQ / 4);
#pragma unroll
    for (int g = 0; g < 4; ++g) {
        int vidx  = g * 256 + tid;
        int slot0 = vidx * 4;
        int base  = SKEW(slot0);   // slot0..slot0+3 share the same >>5 group
        int4 pv;
        pv.x = pos_s[base + 0];
        pv.y = pos_s[base + 1];
        pv.z = pos_s[base + 2];
        pv.w = pos_s[base + 3];
        pout4[vidx] = pv;
    }

    if (tid == 0) out[3 * BS + (size_t)b] = total;
}

extern "C" void kernel_launch(void* const* d_in, const int* in_sizes, int n_in,
                              void* d_out, int out_size, void* d_ws, size_t ws_size,
                              hipStream_t stream) {
    const float* scales     = (const float*)d_in[0];
    const float* rand_tops  = (const float*)d_in[1];
    const float* rand_lefts = (const float*)d_in[2];
    int* out = (int*)d_out;
    int B = in_sizes[0] / NBLK;   // 32768/4 = 8192
    blockmask_kernel<<<B, 256, 0, stream>>>(scales, rand_tops, rand_lefts, out, B);
}